// Round 10
// baseline (237.256 us; speedup 1.0000x reference)
//
#include <hip/hip_runtime.h>

// MHA forward, B=2, S=2048, D=1024, H=16, Dk=64, causal, RoPE. fp32 I/O.
// Internal bf16 MFMA 16x16x32, fp32 accum.
// History: R12/R13 un-paired attn FALSIFIED (spills / dispatch imbalance);
// R14/R15/R19 inner-loop rewrites NEUTRAL (72us pinned at 2 waves/SIMD);
// R17/R18 512-thread attn FALSIFIED (forced-bound spills / barrier convoy).
// R20 WIN: QKV GEMM -> 256x192 dbuf 2-phase, 228->217us.
// R21: attn occupancy via EQUAL-WORK KV-split. Each pair (qtA, qtB=31-qtA)
// = 33 procs split 16/17: e=0 walks KV 0..15 (full tile A incl diag +
// tile B j<=14-qtA), e=1 walks 15-qtA..31-qtA (17 B procs incl diag).
// 1024 equal blocks -> 4 blocks/CU from actual VGPR (~104), no forced
// bounds. Unnormalized softmax => partials merge by ADDITION: tile A
// written complete by e=0; tile B atomicAdd'd (f32) into zeroed P/S in
// d_out (dead xb region) -- exactly 2 adds/elem from 0 => deterministic.
// merge_norm kernel normalizes rows 1024..2047 into qbuf before proj.

typedef unsigned short u16;
typedef __attribute__((ext_vector_type(8))) short short8;   // 8 bf16 = 4 VGPRs
typedef __attribute__((ext_vector_type(4))) float float4v;  // MFMA C/D

typedef const __attribute__((address_space(1))) void GV;    // global
typedef __attribute__((address_space(3))) void LV;          // LDS

#define VSTR 72   // attn Vt row stride (u16): 144B rows, 2-way read banks
#define QSCL 0.18033688011112042f   // 0.125 * log2(e)

__device__ __forceinline__ u16 f2b(float f) {
    union { float f; unsigned int i; } t; t.f = f;
    unsigned int r = t.i + 0x7fffu + ((t.i >> 16) & 1u);   // RNE
    return (u16)(r >> 16);
}

// ---------------- fused fp32 -> bf16 converter ------------------------------
__global__ __launch_bounds__(256) void cvt_all(
    const float4* __restrict__ x,  const float4* __restrict__ wq,
    const float4* __restrict__ wk, const float4* __restrict__ wv,
    const float4* __restrict__ wo,
    u16* __restrict__ xb, u16* __restrict__ wcat, u16* __restrict__ wob)
{
    const int i = blockIdx.x * 256 + threadIdx.x;
    const float4* s; u16* d; int off;
    if (i < 524288) { s = x; d = xb; off = i; }
    else {
        const int widx = i - 524288;
        const int w = widx >> 17, o = widx & 131071;
        switch (w) {
            case 0:  s = wq; d = wcat;              break;
            case 1:  s = wk; d = wcat + (1 << 20);  break;
            case 2:  s = wv; d = wcat + (2 << 20);  break;
            default: s = wo; d = wob;               break;
        }
        off = o;
    }
    float4 a = s[2 * off], b = s[2 * off + 1];
    u16 t[8] = {f2b(a.x), f2b(a.y), f2b(a.z), f2b(a.w),
                f2b(b.x), f2b(b.y), f2b(b.z), f2b(b.w)};
    reinterpret_cast<int4*>(d)[off] = *reinterpret_cast<int4*>(t);
}

// ---------------- RoPE cos/sin table: tab[pos*32+fi] = {cos, sin} ----------
__global__ __launch_bounds__(256) void rope_tab(float2* __restrict__ tab) {
    const int i = blockIdx.x * 256 + threadIdx.x;   // 0..65535
    const int pos = i >> 5, fi = i & 31;
    const float freq = exp2f((float)fi * -0.4152410118609203f);  // -log2(1e4)/32
    float sn, cs; sincosf((float)pos * freq, &sn, &cs);
    tab[i] = make_float2(cs, sn);
}

// ---------------- zero-fill for P/S partial buffers -------------------------
__global__ __launch_bounds__(256) void zerows(float4* __restrict__ p) {
    p[blockIdx.x * 256 + threadIdx.x] = (float4){0.f, 0.f, 0.f, 0.f};
}

// ---------------------------------------------------------------------------
// QKV GEMM: 256(m) x 192(n) x 64(k) steps, 512 threads, 8 waves (2m x 4n),
// double-buffered LDS (112KB), 2-phase: stage(kb+1) before compute(kb),
// one barrier/step. Grid 256 = 1 block/CU. RoPE epilogue.
// ---------------------------------------------------------------------------
__global__ __launch_bounds__(512) void gemm_qkv(
    const u16* __restrict__ X, const u16* __restrict__ Wb,
    u16* __restrict__ Yq, u16* __restrict__ Yk, u16* __restrict__ Yv,
    const float2* __restrict__ tab)
{
    __shared__ u16 As[2][256 * 64];   // 2 x 32KB
    __shared__ u16 Bs[2][192 * 64];   // 2 x 24KB

    const int tid  = threadIdx.x;
    const int wave = tid >> 6;                          // 0..7
    const int lane = tid & 63;
    const int quad = lane >> 4;
    const int l16  = lane & 15;
    const int wm = (wave >> 2) * 128;                   // 0,128
    const int wn = (wave & 3) * 48;                     // 0,48,96,144
    const int g = blockIdx.x;
    const int rr = g >> 3;                              // 0..31
    const int m0 = ((g & 7) * 2 + (rr >> 4)) * 256;     // 16 m-tiles
    const int n0 = (rr & 15) * 192;                     // 16 n-tiles
    const int lrow = lane >> 3;                         // 0..7 within 8-row slab
    const int cg8  = (lane & 7) ^ lrow;                 // swizzled global unit

    float4v acc[8][3];
#pragma unroll
    for (int mt = 0; mt < 8; mt++)
#pragma unroll
        for (int nt = 0; nt < 3; nt++) acc[mt][nt] = (float4v){0.f, 0.f, 0.f, 0.f};

    auto stage = [&](int bsel, int kb) {
#pragma unroll
        for (int t = 0; t < 4; t++) {                   // A: 32 slabs of 8 rows
            const int I = wave * 4 + t;
            const u16* gp = X + (size_t)(m0 + I * 8 + lrow) * 1024 + kb + cg8 * 8;
            __builtin_amdgcn_global_load_lds((GV*)gp, (LV*)&As[bsel][I * 512], 16, 0, 0);
        }
#pragma unroll
        for (int t = 0; t < 3; t++) {                   // B: 24 slabs of 8 rows
            const int I = wave * 3 + t;
            const u16* gp = Wb + (size_t)(n0 + I * 8 + lrow) * 1024 + kb + cg8 * 8;
            __builtin_amdgcn_global_load_lds((GV*)gp, (LV*)&Bs[bsel][I * 512], 16, 0, 0);
        }
    };

    stage(0, 0);
    __syncthreads();                                    // drain vmcnt (buf0 ready)

    for (int kbi = 0; kbi < 16; kbi++) {
        const int cur = kbi & 1;
        if (kbi < 15) stage(cur ^ 1, (kbi + 1) * 64);   // prefetch next K-step
#pragma unroll
        for (int ks = 0; ks < 2; ks++) {
            const int su = ((ks * 4 + quad) ^ (l16 & 7)) * 8;   // swizzled unit
            short8 af[8], bf[3];
#pragma unroll
            for (int t = 0; t < 8; t++)
                af[t] = *reinterpret_cast<const short8*>(&As[cur][(wm + t * 16 + l16) * 64 + su]);
#pragma unroll
            for (int t = 0; t < 3; t++)
                bf[t] = *reinterpret_cast<const short8*>(&Bs[cur][(wn + t * 16 + l16) * 64 + su]);
#pragma unroll
            for (int mt = 0; mt < 8; mt++)
#pragma unroll
                for (int nt = 0; nt < 3; nt++)
                    acc[mt][nt] = __builtin_amdgcn_mfma_f32_16x16x32_bf16(af[mt], bf[nt], acc[mt][nt], 0, 0, 0);
        }
        __syncthreads();   // drains vmcnt (next buf staged) + lgkm; flip
    }

    // RoPE epilogue
#pragma unroll
    for (int nt = 0; nt < 3; nt++) {
        const int cg = n0 + wn + nt * 16 + l16;      // global col 0..3071
        const int buf = cg >> 10;                    // 0=q 1=k 2=v
        const int c = cg & 1023;
        u16* dst = (buf == 0) ? Yq : ((buf == 1) ? Yk : Yv);
        const bool rp = (buf < 2);
        const float scl = (buf == 0) ? QSCL : 1.0f;
        const int fi = (cg & 63) >> 1;               // pair index in head
#pragma unroll
        for (int mt = 0; mt < 8; mt++)
#pragma unroll
            for (int r = 0; r < 4; r++) {
                const int row = m0 + wm + mt * 16 + quad * 4 + r;
                float v = acc[mt][nt][r];
                if (rp) {
                    const float2 t = tab[((row & 2047) << 5) + fi];
                    const float partner = __shfl_xor(v, 1);
                    v = (l16 & 1) ? fmaf(v, t.x,  partner * t.y)
                                  : fmaf(v, t.x, -partner * t.y);
                }
                dst[(size_t)row * 1024 + c] = f2b(v * scl);
            }
    }
}

// ---------------------------------------------------------------------------
// Out-proj GEMM (m97-class): 128(m) x NT*32(n) x 64(k).
// ---------------------------------------------------------------------------
template<int NT, int NBLK>
__global__ __launch_bounds__(256) void gemm_tile(
    const u16* __restrict__ X, const u16* __restrict__ Wb,
    float* __restrict__ Yf)
{
    __shared__ u16 As[128 * 64];
    __shared__ u16 Bs[NT * 32 * 64];

    const int tid  = threadIdx.x;
    const int wave = tid >> 6;
    const int lane = tid & 63;
    const int quad = lane >> 4;
    const int l16  = lane & 15;
    const int wm = (wave >> 1) * 64, wn = (wave & 1) * (NT * 16);
    const int g = blockIdx.x;
    const int rr = g >> 3;
    const int m0 = ((g & 7) * 4 + rr / NBLK) * 128;
    const int n0 = (rr % NBLK) * (NT * 32);
    const int lrow = lane >> 3;                         // 0..7 within 8-row slab
    const int cg8  = (lane & 7) ^ lrow;                 // swizzled global unit

    float4v acc[4][NT];
#pragma unroll
    for (int mt = 0; mt < 4; mt++)
#pragma unroll
        for (int nt = 0; nt < NT; nt++) acc[mt][nt] = (float4v){0.f, 0.f, 0.f, 0.f};

    for (int kb = 0; kb < 1024; kb += 64) {
        __syncthreads();                                 // prev reads done
#pragma unroll
        for (int t = 0; t < 4; t++) {                    // stage A: 4x 1KB/wave
            const int I = wave * 4 + t;
            const u16* gp = X + (size_t)(m0 + I * 8 + lrow) * 1024 + kb + cg8 * 8;
            __builtin_amdgcn_global_load_lds((GV*)gp, (LV*)&As[I * 512], 16, 0, 0);
        }
#pragma unroll
        for (int t = 0; t < NT; t++) {                   // stage B: NTx 1KB/wave
            const int I = wave * NT + t;
            const u16* gp = Wb + (size_t)(n0 + I * 8 + lrow) * 1024 + kb + cg8 * 8;
            __builtin_amdgcn_global_load_lds((GV*)gp, (LV*)&Bs[I * 512], 16, 0, 0);
        }
        __syncthreads();                                 // vmcnt drained here
#pragma unroll
        for (int ks = 0; ks < 2; ks++) {
            const int su = ((ks * 4 + quad) ^ (l16 & 7)) * 8;   // swizzled unit
            short8 af[4], bf[NT];
#pragma unroll
            for (int t = 0; t < 4; t++)
                af[t] = *reinterpret_cast<const short8*>(&As[(wm + t * 16 + l16) * 64 + su]);
#pragma unroll
            for (int t = 0; t < NT; t++)
                bf[t] = *reinterpret_cast<const short8*>(&Bs[(wn + t * 16 + l16) * 64 + su]);
#pragma unroll
            for (int mt = 0; mt < 4; mt++)
#pragma unroll
                for (int nt = 0; nt < NT; nt++)
                    acc[mt][nt] = __builtin_amdgcn_mfma_f32_16x16x32_bf16(af[mt], bf[nt], acc[mt][nt], 0, 0, 0);
        }
    }

#pragma unroll
    for (int nt = 0; nt < NT; nt++) {
        const int col = n0 + wn + nt * 16 + l16;
#pragma unroll
        for (int mt = 0; mt < 4; mt++)
#pragma unroll
            for (int r = 0; r < 4; r++) {
                const int row = m0 + wm + mt * 16 + quad * 4 + r;
                Yf[(size_t)row * 1024 + col] = acc[mt][nt][r];
            }
    }
}

// ---------------------------------------------------------------------------
// Flash causal attention, KV-split pairs: 1024 EQUAL blocks, 256 threads.
// Block (G, p, e): qtA=p, qtB=31-p. e=0: KV j=0..15, full tile A (diag at
// qtA) + tile B for j<=14-qtA (16 procs / 16 iters). e=1: KV j=15-qtA..
// 31-qtA, 17 single-B procs incl diag (17 iters). Tile A written complete
// by e=0 (normalized). Tile B: f32 partials atomicAdd'd into P/S (exactly
// 2 adds/elem from 0 => order-independent). Swapped QK^T + sigma-PV (R19),
// dbuf Vt, one barrier/iter, K direct from global (prefetched). O aliases
// Q: e=0 writes rows of its OWN tile A only; no cross-block hazard.
// ---------------------------------------------------------------------------
__global__ __launch_bounds__(256, 2) void attn_kernel(
    const u16* Q, const u16* __restrict__ K,
    const u16* __restrict__ V, u16* O,
    float* __restrict__ P, float* __restrict__ S)
{
    __shared__ __align__(16) u16 Vt[2][64 * VSTR];   // Vt[b][d][s^((d>>4)<<4)]

    const int tid  = threadIdx.x;
    const int wave = tid >> 6;
    const int lane = tid & 63;
    const int quad = lane >> 4;
    const int l16  = lane & 15;
    const int g = blockIdx.x;
    const int xcd = g & 7, slot = g >> 3;   // slot 0..127
    const int e   = slot & 1;               // KV half
    const int p   = (slot >> 1) & 15;       // pair
    const int G   = (slot >> 5) * 8 + xcd;  // 0..31 = (b,h) group
    const int qtA = p;
    const int qtB = 31 - p;
    const int jbeg = e ? (15 - qtA) : 0;
    const int jend = e ? (31 - qtA) : 15;
    const int L = jend - jbeg;              // 16 (e=1) or 15 (e=0)
    const int b = G & 1, h = G >> 1;
    const size_t base = ((size_t)b * 2048) * 1024 + (size_t)h * 64;

    short8 qfA[2], qfB[2];
    if (!e) {
        const size_t ra = base + (size_t)(qtA * 64 + wave * 16 + l16) * 1024;
        qfA[0] = *reinterpret_cast<const short8*>(Q + ra + quad * 8);
        qfA[1] = *reinterpret_cast<const short8*>(Q + ra + 32 + quad * 8);
    }
    {
        const size_t rb = base + (size_t)(qtB * 64 + wave * 16 + l16) * 1024;
        qfB[0] = *reinterpret_cast<const short8*>(Q + rb + quad * 8);
        qfB[1] = *reinterpret_cast<const short8*>(Q + rb + 32 + quad * 8);
    }

    float4v oA[4], oB[4];
#pragma unroll
    for (int i = 0; i < 4; i++) { oA[i] = (float4v){0.f,0.f,0.f,0.f}; oB[i] = (float4v){0.f,0.f,0.f,0.f}; }
    float sA = 0.f, sB = 0.f;               // row-sum partial for q = wave*16+l16

    const int srow = tid >> 2;             // 0..63 (coalesced: 4 lanes/row)
    const int cb   = (tid & 3) << 4;       // 0,16,32,48
    const int sxw  = srow ^ cb;            // swizzled s ((d>>4)<<4 == cb)

    const u16* Vp = V + base + (size_t)srow * 1024 + cb;
    const u16* kbase = K + base + (size_t)l16 * 1024 + quad * 8;
    int4 vr0 = *reinterpret_cast<const int4*>(Vp + (size_t)jbeg * 65536);
    int4 vr1 = *reinterpret_cast<const int4*>(Vp + (size_t)jbeg * 65536 + 8);
    short8 kn[4][2], kc[4][2], vf[4][2];
#pragma unroll
    for (int nt = 0; nt < 4; nt++)                          // K tile jbeg
#pragma unroll
        for (int ks = 0; ks < 2; ks++)
            kn[nt][ks] = *reinterpret_cast<const short8*>(kbase + (size_t)jbeg * 65536 + (size_t)(nt * 16) * 1024 + ks * 32);

    // prologue: stage tile jbeg -> Vt[0]; vr <- tile jbeg+1 (L >= 15)
    {
        const u16* a = reinterpret_cast<const u16*>(&vr0);
        const u16* c = reinterpret_cast<const u16*>(&vr1);
#pragma unroll
        for (int ee = 0; ee < 8; ee++) Vt[0][(cb + ee) * VSTR + sxw] = a[ee];
#pragma unroll
        for (int ee = 0; ee < 8; ee++) Vt[0][(cb + 8 + ee) * VSTR + sxw] = c[ee];
    }
    vr0 = *reinterpret_cast<const int4*>(Vp + (size_t)(jbeg + 1) * 65536);
    vr1 = *reinterpret_cast<const int4*>(Vp + (size_t)(jbeg + 1) * 65536 + 8);

    const int qloc = wave * 16 + l16;      // this lane's q within its tile

    // SWAPPED QK: sacc[nt][r] = S[q=qloc][k = nt*16 + quad*4 + r]
    auto qk = [&](const short8 (&qf)[2], float4v (&sacc)[4]) {
#pragma unroll
        for (int nt = 0; nt < 4; nt++) {
            sacc[nt] = (float4v){0.f, 0.f, 0.f, 0.f};
#pragma unroll
            for (int ks = 0; ks < 2; ks++)
                sacc[nt] = __builtin_amdgcn_mfma_f32_16x16x32_bf16(kc[nt][ks], qf[ks], sacc[nt], 0, 0, 0);
        }
    };
    auto smx = [&](const float4v (&sacc)[4], float &sr, short8 (&pa)[2], bool diag) {
        unsigned int w[4][2];
#pragma unroll
        for (int nt = 0; nt < 4; nt++) {
            float pp[4];
#pragma unroll
            for (int r = 0; r < 4; r++) {
                float sv = sacc[nt][r];                      // log2-domain
                if (diag && (nt * 16 + quad * 4 + r > qloc)) sv = -1e30f;
                pp[r] = exp2f(sv);                           // masked -> 0
                sr += pp[r];
            }
            asm("v_cvt_pk_bf16_f32 %0, %1, %2" : "=v"(w[nt][0]) : "v"(pp[0]), "v"(pp[1]));
            asm("v_cvt_pk_bf16_f32 %0, %1, %2" : "=v"(w[nt][1]) : "v"(pp[2]), "v"(pp[3]));
        }
        union { unsigned int u[4]; short8 s8; } t;
        t.u[0] = w[0][0]; t.u[1] = w[0][1]; t.u[2] = w[1][0]; t.u[3] = w[1][1];
        pa[0] = t.s8;
        t.u[0] = w[2][0]; t.u[1] = w[2][1]; t.u[2] = w[3][0]; t.u[3] = w[3][1];
        pa[1] = t.s8;
    };
    auto pv = [&](const short8 (&pa)[2], float4v (&oc)[4]) {
#pragma unroll
        for (int ks = 0; ks < 2; ks++)
#pragma unroll
            for (int dt = 0; dt < 4; dt++)
                oc[dt] = __builtin_amdgcn_mfma_f32_16x16x32_bf16(pa[ks], vf[dt][ks], oc[dt], 0, 0, 0);
    };

    for (int jj = 0; jj <= L; jj++) {
        const int j = jbeg + jj;
        __syncthreads();   // protects Vt[(jj+1)&1]: its iter-(jj-1) readers done
        if (jj < L) {      // stage tile j+1 (in vr) -> Vt[(jj+1)&1]
            u16* D = Vt[(jj + 1) & 1];
            const u16* a = reinterpret_cast<const u16*>(&vr0);
            const u16* c = reinterpret_cast<const u16*>(&vr1);
#pragma unroll
            for (int ee = 0; ee < 8; ee++) D[(cb + ee) * VSTR + sxw] = a[ee];
#pragma unroll
            for (int ee = 0; ee < 8; ee++) D[(cb + 8 + ee) * VSTR + sxw] = c[ee];
        }
#pragma unroll
        for (int nt = 0; nt < 4; nt++)
#pragma unroll
            for (int ks = 0; ks < 2; ks++) kc[nt][ks] = kn[nt][ks];
        if (jj < L) {      // prefetch: V tile j+2, K tile j+1
            if (jj + 2 <= L) {
                vr0 = *reinterpret_cast<const int4*>(Vp + (size_t)(j + 2) * 65536);
                vr1 = *reinterpret_cast<const int4*>(Vp + (size_t)(j + 2) * 65536 + 8);
            }
            const u16* kb2 = kbase + (size_t)(j + 1) * 65536;
#pragma unroll
            for (int nt = 0; nt < 4; nt++)
#pragma unroll
                for (int ks = 0; ks < 2; ks++)
                    kn[nt][ks] = *reinterpret_cast<const short8*>(kb2 + (size_t)(nt * 16) * 1024 + ks * 32);
        }

        const bool actA = (!e) && (j <= qtA);
        const bool actB = e ? true : (j <= 14 - qtA);
        if (actA || actB) {
            // vf from Vt[jj&1], sigma'd k-order (R19)
            const u16* Bt = Vt[jj & 1];
#pragma unroll
            for (int dt = 0; dt < 4; dt++) {
                const int rb = (dt * 16 + l16) * VSTR;
#pragma unroll
                for (int ks = 0; ks < 2; ks++) {
                    const int k1 = (ks * 32 + quad * 4) ^ (dt << 4);
                    const int k2 = (ks * 32 + 16 + quad * 4) ^ (dt << 4);
                    union { struct { uint2 lo, hi; } pr; short8 s8; } u;
                    u.pr.lo = *reinterpret_cast<const uint2*>(&Bt[rb + k1]);
                    u.pr.hi = *reinterpret_cast<const uint2*>(&Bt[rb + k2]);
                    vf[dt][ks] = u.s8;
                }
            }
            if (actA) {
                float4v xA[4]; short8 paA[2];
                qk(qfA, xA);
                smx(xA, sA, paA, j == qtA);
                pv(paA, oA);
            }
            if (actB) {
                float4v xB[4]; short8 paB[2];
                qk(qfB, xB);
                smx(xB, sB, paB, j == qtB);   // diag reachable only when e=1
                pv(paB, oB);
            }
        }
    }

    // epilogue A (e=0 only): complete -> normalize + write
    if (!e) {
        float tA = sA;
        tA += __shfl_xor(tA, 16); tA += __shfl_xor(tA, 32);
#pragma unroll
        for (int r = 0; r < 4; r++) {
            const int rl = quad * 4 + r;
            const float invA = 1.0f / __shfl(tA, rl);
            const size_t rowA = base + (size_t)(qtA * 64 + wave * 16 + rl) * 1024;
#pragma unroll
            for (int dt = 0; dt < 4; dt++)
                O[rowA + dt * 16 + l16] = f2b(oA[dt][r] * invA);
        }
    }
    // epilogue B (both halves): deterministic 2-add atomic merge
    float tB = sB;
    tB += __shfl_xor(tB, 16); tB += __shfl_xor(tB, 32);
    float* Pb = P + (size_t)((G * 16 + (qtB - 16)) * 64) * 64;
#pragma unroll
    for (int dt = 0; dt < 4; dt++)
#pragma unroll
        for (int r = 0; r < 4; r++)
            atomicAdd(&Pb[(wave * 16 + quad * 4 + r) * 64 + dt * 16 + l16], oB[dt][r]);
    if (quad == 0)
        atomicAdd(&S[(G * 16 + (qtB - 16)) * 64 + wave * 16 + l16], tB);
}

// ---------------------------------------------------------------------------
// merge B-tile partials: O rows 1024..2047 per b = f2b(P / S)
// ---------------------------------------------------------------------------
__global__ __launch_bounds__(256) void merge_norm(
    const float* __restrict__ P, const float* __restrict__ S,
    u16* __restrict__ O)
{
    const int i = blockIdx.x * 256 + threadIdx.x;   // 0..524287
    const int d4  = i & 15;
    const int row = (i >> 4) & 63;
    const int t   = (i >> 10) & 15;
    const int G   = i >> 14;                        // 0..31
    const float4 v = *reinterpret_cast<const float4*>(
        &P[((size_t)((G * 16 + t) * 64 + row)) * 64 + d4 * 4]);
    const float inv = 1.0f / S[(G * 16 + t) * 64 + row];
    const int b = G & 1, h = G >> 1;
    const size_t addr = (size_t)b * 2048 * 1024
                      + (size_t)((t + 16) * 64 + row) * 1024 + h * 64 + d4 * 4;
    u16 o4[4] = {f2b(v.x * inv), f2b(v.y * inv), f2b(v.z * inv), f2b(v.w * inv)};
    *reinterpret_cast<uint2*>(&O[addr]) = *reinterpret_cast<uint2*>(o4);
}

// ---------------------------------------------------------------------------
extern "C" void kernel_launch(void* const* d_in, const int* in_sizes, int n_in,
                              void* d_out, int out_size, void* d_ws, size_t ws_size,
                              hipStream_t stream) {
    (void)in_sizes; (void)n_in; (void)out_size; (void)ws_size;
    const float* x  = (const float*)d_in[0];
    const float* wq = (const float*)d_in[1];
    const float* wk = (const float*)d_in[2];
    const float* wv = (const float*)d_in[3];
    const float* wo = (const float*)d_in[4];

    const size_t MN = (size_t)4096 * 1024;

    // d_out (16.7MB): phase 1: xb (8.4MB) + wcat (6.3MB) + tab (0.5MB);
    // phase 2 (post-qkv, all dead): P (8.39MB) + S (0.13MB) partials;
    // phase 3: proj output overwrites everything.
    u16* xb   = (u16*)d_out;
    u16* wcat = xb + MN;                    // [3072][1024] = wq|wk|wv rows
    float2* tab = (float2*)(wcat + (size_t)3072 * 1024);
    float* Pp = (float*)d_out;              // [32][16][64][64] f32
    float* Sp = Pp + (size_t)32 * 16 * 64 * 64;   // [32][16][64] f32
    u16* qbuf = (u16*)d_ws;                 // also attention output
    u16* kbuf = qbuf + MN;
    u16* vbuf = kbuf + MN;
    u16* wob  = vbuf + MN;                  // ws total: 26MB

    cvt_all<<<4096, 256, 0, stream>>>((const float4*)x, (const float4*)wq,
                                      (const float4*)wk, (const float4*)wv,
                                      (const float4*)wo, xb, wcat, wob);
    rope_tab<<<256, 256, 0, stream>>>(tab);
    gemm_qkv<<<256, 512, 0, stream>>>(xb, wcat, qbuf, kbuf, vbuf, tab);
    zerows<<<2080, 256, 0, stream>>>((float4*)Pp);   // P+S = 532480 float4
    attn_kernel<<<1024, 256, 0, stream>>>(qbuf, kbuf, vbuf, qbuf, Pp, Sp);
    merge_norm<<<2048, 256, 0, stream>>>(Pp, Sp, qbuf);
    gemm_tile<2, 16><<<512, 256, 0, stream>>>(qbuf, wob, (float*)d_out);
}

// Round 11
// 218.193 us; speedup vs baseline: 1.0874x; 1.0874x over previous
//
#include <hip/hip_runtime.h>

// MHA forward, B=2, S=2048, D=1024, H=16, Dk=64, causal, RoPE. fp32 I/O.
// Internal bf16 MFMA 16x16x32, fp32 accum.
// History: attn is FROZEN at the R19 form (70.5us): R12/R13 (un-pair),
// R17/R18 (8-wave), R21 (KV-split + atomic merge) all FALSIFIED; R14/R15/
// R19 inner rewrites NEUTRAL -- 2-waves/SIMD latency floor ~5.1k cy/iter.
// R20 WIN: QKV -> 256x192 dbuf 2-phase 1-blk/CU (228->217us).
// R22: (a) revert attn to R20 exactly; (b) port proj GEMM to the same
// dbuf 2-phase structure: 256x64 tile, grid 16x16=256=1/CU, 512 thr,
// 8 waves (4m x 2n), acc[4][2], LDS 2x(32+8)=80KB, stage(k+1) before
// compute(k), one barrier/step; (c) fuse rope_tab into cvt_all (block-
// granular branch) -- one launch fewer. 4 launches total.

typedef unsigned short u16;
typedef __attribute__((ext_vector_type(8))) short short8;   // 8 bf16 = 4 VGPRs
typedef __attribute__((ext_vector_type(4))) float float4v;  // MFMA C/D

typedef const __attribute__((address_space(1))) void GV;    // global
typedef __attribute__((address_space(3))) void LV;          // LDS

#define VSTR 72   // attn Vt row stride (u16): 144B rows, 2-way read banks
#define QSCL 0.18033688011112042f   // 0.125 * log2(e)

__device__ __forceinline__ u16 f2b(float f) {
    union { float f; unsigned int i; } t; t.f = f;
    unsigned int r = t.i + 0x7fffu + ((t.i >> 16) & 1u);   // RNE
    return (u16)(r >> 16);
}

// ---------------- fused fp32 -> bf16 converter + RoPE table -----------------
// blocks 0..4095: cvt x/wq/wk/wv/wo. blocks 4096..4351: tab[pos*32+fi].
__global__ __launch_bounds__(256) void cvt_all(
    const float4* __restrict__ x,  const float4* __restrict__ wq,
    const float4* __restrict__ wk, const float4* __restrict__ wv,
    const float4* __restrict__ wo,
    u16* __restrict__ xb, u16* __restrict__ wcat, u16* __restrict__ wob,
    float2* __restrict__ tab)
{
    const int blk = blockIdx.x;
    if (blk >= 4096) {                 // RoPE cos/sin table
        const int i = (blk - 4096) * 256 + threadIdx.x;   // 0..65535
        const int pos = i >> 5, fi = i & 31;
        const float freq = exp2f((float)fi * -0.4152410118609203f);  // -log2(1e4)/32
        float sn, cs; sincosf((float)pos * freq, &sn, &cs);
        tab[i] = make_float2(cs, sn);
        return;
    }
    const int i = blk * 256 + threadIdx.x;
    const float4* s; u16* d; int off;
    if (i < 524288) { s = x; d = xb; off = i; }
    else {
        const int widx = i - 524288;
        const int w = widx >> 17, o = widx & 131071;
        switch (w) {
            case 0:  s = wq; d = wcat;              break;
            case 1:  s = wk; d = wcat + (1 << 20);  break;
            case 2:  s = wv; d = wcat + (2 << 20);  break;
            default: s = wo; d = wob;               break;
        }
        off = o;
    }
    float4 a = s[2 * off], b = s[2 * off + 1];
    u16 t[8] = {f2b(a.x), f2b(a.y), f2b(a.z), f2b(a.w),
                f2b(b.x), f2b(b.y), f2b(b.z), f2b(b.w)};
    reinterpret_cast<int4*>(d)[off] = *reinterpret_cast<int4*>(t);
}

// ---------------------------------------------------------------------------
// QKV GEMM: 256(m) x 192(n) x 64(k) steps, 512 threads, 8 waves (2m x 4n),
// double-buffered LDS (112KB), 2-phase: stage(kb+1) before compute(kb),
// one barrier/step. Grid 256 = 1 block/CU. RoPE epilogue.
// ---------------------------------------------------------------------------
__global__ __launch_bounds__(512) void gemm_qkv(
    const u16* __restrict__ X, const u16* __restrict__ Wb,
    u16* __restrict__ Yq, u16* __restrict__ Yk, u16* __restrict__ Yv,
    const float2* __restrict__ tab)
{
    __shared__ u16 As[2][256 * 64];   // 2 x 32KB
    __shared__ u16 Bs[2][192 * 64];   // 2 x 24KB

    const int tid  = threadIdx.x;
    const int wave = tid >> 6;                          // 0..7
    const int lane = tid & 63;
    const int quad = lane >> 4;
    const int l16  = lane & 15;
    const int wm = (wave >> 2) * 128;                   // 0,128
    const int wn = (wave & 3) * 48;                     // 0,48,96,144
    const int g = blockIdx.x;
    const int rr = g >> 3;                              // 0..31
    const int m0 = ((g & 7) * 2 + (rr >> 4)) * 256;     // 16 m-tiles
    const int n0 = (rr & 15) * 192;                     // 16 n-tiles
    const int lrow = lane >> 3;                         // 0..7 within 8-row slab
    const int cg8  = (lane & 7) ^ lrow;                 // swizzled global unit

    float4v acc[8][3];
#pragma unroll
    for (int mt = 0; mt < 8; mt++)
#pragma unroll
        for (int nt = 0; nt < 3; nt++) acc[mt][nt] = (float4v){0.f, 0.f, 0.f, 0.f};

    auto stage = [&](int bsel, int kb) {
#pragma unroll
        for (int t = 0; t < 4; t++) {                   // A: 32 slabs of 8 rows
            const int I = wave * 4 + t;
            const u16* gp = X + (size_t)(m0 + I * 8 + lrow) * 1024 + kb + cg8 * 8;
            __builtin_amdgcn_global_load_lds((GV*)gp, (LV*)&As[bsel][I * 512], 16, 0, 0);
        }
#pragma unroll
        for (int t = 0; t < 3; t++) {                   // B: 24 slabs of 8 rows
            const int I = wave * 3 + t;
            const u16* gp = Wb + (size_t)(n0 + I * 8 + lrow) * 1024 + kb + cg8 * 8;
            __builtin_amdgcn_global_load_lds((GV*)gp, (LV*)&Bs[bsel][I * 512], 16, 0, 0);
        }
    };

    stage(0, 0);
    __syncthreads();                                    // drain vmcnt (buf0 ready)

    for (int kbi = 0; kbi < 16; kbi++) {
        const int cur = kbi & 1;
        if (kbi < 15) stage(cur ^ 1, (kbi + 1) * 64);   // prefetch next K-step
#pragma unroll
        for (int ks = 0; ks < 2; ks++) {
            const int su = ((ks * 4 + quad) ^ (l16 & 7)) * 8;   // swizzled unit
            short8 af[8], bf[3];
#pragma unroll
            for (int t = 0; t < 8; t++)
                af[t] = *reinterpret_cast<const short8*>(&As[cur][(wm + t * 16 + l16) * 64 + su]);
#pragma unroll
            for (int t = 0; t < 3; t++)
                bf[t] = *reinterpret_cast<const short8*>(&Bs[cur][(wn + t * 16 + l16) * 64 + su]);
#pragma unroll
            for (int mt = 0; mt < 8; mt++)
#pragma unroll
                for (int nt = 0; nt < 3; nt++)
                    acc[mt][nt] = __builtin_amdgcn_mfma_f32_16x16x32_bf16(af[mt], bf[nt], acc[mt][nt], 0, 0, 0);
        }
        __syncthreads();   // drains vmcnt (next buf staged) + lgkm; flip
    }

    // RoPE epilogue
#pragma unroll
    for (int nt = 0; nt < 3; nt++) {
        const int cg = n0 + wn + nt * 16 + l16;      // global col 0..3071
        const int buf = cg >> 10;                    // 0=q 1=k 2=v
        const int c = cg & 1023;
        u16* dst = (buf == 0) ? Yq : ((buf == 1) ? Yk : Yv);
        const bool rp = (buf < 2);
        const float scl = (buf == 0) ? QSCL : 1.0f;
        const int fi = (cg & 63) >> 1;               // pair index in head
#pragma unroll
        for (int mt = 0; mt < 8; mt++)
#pragma unroll
            for (int r = 0; r < 4; r++) {
                const int row = m0 + wm + mt * 16 + quad * 4 + r;
                float v = acc[mt][nt][r];
                if (rp) {
                    const float2 t = tab[((row & 2047) << 5) + fi];
                    const float partner = __shfl_xor(v, 1);
                    v = (l16 & 1) ? fmaf(v, t.x,  partner * t.y)
                                  : fmaf(v, t.x, -partner * t.y);
                }
                dst[(size_t)row * 1024 + c] = f2b(v * scl);
            }
    }
}

// ---------------------------------------------------------------------------
// Out-proj GEMM (R22): 256(m) x 64(n) x 64(k) steps, 512 threads, 8 waves
// (4m x 2n), acc[4][2], double-buffered LDS (80KB), 2-phase like gemm_qkv.
// Grid 256 = 16m x 16n = 1 block/CU. f32 output.
// ---------------------------------------------------------------------------
__global__ __launch_bounds__(512) void gemm_proj(
    const u16* __restrict__ X, const u16* __restrict__ Wb,
    float* __restrict__ Yf)
{
    __shared__ u16 As[2][256 * 64];   // 2 x 32KB
    __shared__ u16 Bs[2][64 * 64];    // 2 x 8KB

    const int tid  = threadIdx.x;
    const int wave = tid >> 6;                          // 0..7
    const int lane = tid & 63;
    const int quad = lane >> 4;
    const int l16  = lane & 15;
    const int wm = (wave >> 1) * 64;                    // 0,64,128,192
    const int wn = (wave & 1) * 32;                     // 0,32
    const int g = blockIdx.x;
    const int rr = g >> 3;                              // 0..31
    const int m0 = ((g & 7) * 2 + (rr >> 4)) * 256;     // 16 m-tiles
    const int n0 = (rr & 15) * 64;                      // 16 n-tiles
    const int lrow = lane >> 3;                         // 0..7 within 8-row slab
    const int cg8  = (lane & 7) ^ lrow;                 // swizzled global unit

    float4v acc[4][2];
#pragma unroll
    for (int mt = 0; mt < 4; mt++)
#pragma unroll
        for (int nt = 0; nt < 2; nt++) acc[mt][nt] = (float4v){0.f, 0.f, 0.f, 0.f};

    auto stage = [&](int bsel, int kb) {
#pragma unroll
        for (int t = 0; t < 4; t++) {                   // A: 32 slabs of 8 rows
            const int I = wave * 4 + t;
            const u16* gp = X + (size_t)(m0 + I * 8 + lrow) * 1024 + kb + cg8 * 8;
            __builtin_amdgcn_global_load_lds((GV*)gp, (LV*)&As[bsel][I * 512], 16, 0, 0);
        }
        {                                               // B: 8 slabs, 1/wave
            const u16* gp = Wb + (size_t)(n0 + wave * 8 + lrow) * 1024 + kb + cg8 * 8;
            __builtin_amdgcn_global_load_lds((GV*)gp, (LV*)&Bs[bsel][wave * 512], 16, 0, 0);
        }
    };

    stage(0, 0);
    __syncthreads();                                    // drain vmcnt (buf0 ready)

    for (int kbi = 0; kbi < 16; kbi++) {
        const int cur = kbi & 1;
        if (kbi < 15) stage(cur ^ 1, (kbi + 1) * 64);   // prefetch next K-step
#pragma unroll
        for (int ks = 0; ks < 2; ks++) {
            const int su = ((ks * 4 + quad) ^ (l16 & 7)) * 8;   // swizzled unit
            short8 af[4], bf[2];
#pragma unroll
            for (int t = 0; t < 4; t++)
                af[t] = *reinterpret_cast<const short8*>(&As[cur][(wm + t * 16 + l16) * 64 + su]);
#pragma unroll
            for (int t = 0; t < 2; t++)
                bf[t] = *reinterpret_cast<const short8*>(&Bs[cur][(wn + t * 16 + l16) * 64 + su]);
#pragma unroll
            for (int mt = 0; mt < 4; mt++)
#pragma unroll
                for (int nt = 0; nt < 2; nt++)
                    acc[mt][nt] = __builtin_amdgcn_mfma_f32_16x16x32_bf16(af[mt], bf[nt], acc[mt][nt], 0, 0, 0);
        }
        __syncthreads();   // drains vmcnt (next buf staged) + lgkm; flip
    }

#pragma unroll
    for (int nt = 0; nt < 2; nt++) {
        const int col = n0 + wn + nt * 16 + l16;
#pragma unroll
        for (int mt = 0; mt < 4; mt++)
#pragma unroll
            for (int r = 0; r < 4; r++) {
                const int row = m0 + wm + mt * 16 + quad * 4 + r;
                Yf[(size_t)row * 1024 + col] = acc[mt][nt][r];
            }
    }
}

// ---------------------------------------------------------------------------
// Flash causal attention (FROZEN, R19/R20 form): paired q-tiles (qtA,
// 31-qtA) -> 512 equal-work blocks, 256 threads. Unnormalized softmax
// (q pre-scaled 0.125*log2e, p = exp2f(s)). Swapped QK^T: lane holds
// S[q=wave*16+l16][k=nt*16+quad*4+r]. sigma-PV: pa[ks] = packed own words
// (no cross-lane); vf = 2 x b64 at sigma'd k-offsets. Double-buffered Vt,
// ONE barrier/iter. K frags direct from global, prefetched. XCD grouping:
// 16 blocks of one (b,h) per XCD L2. O aliases Q.
// ---------------------------------------------------------------------------
__global__ __launch_bounds__(256, 2) void attn_kernel(
    const u16* Q, const u16* __restrict__ K,
    const u16* __restrict__ V, u16* O)
{
    __shared__ __align__(16) u16 Vt[2][64 * VSTR];   // Vt[b][d][s^((d>>4)<<4)]

    const int tid  = threadIdx.x;
    const int wave = tid >> 6;
    const int lane = tid & 63;
    const int quad = lane >> 4;
    const int l16  = lane & 15;
    const int g = blockIdx.x;
    const int xcd = g & 7, slot = g >> 3;
    const int G = (slot >> 4) * 8 + xcd;    // 0..31 = (b,h) group
    const int qtA = slot & 15;              // 0..15
    const int qtB = 31 - qtA;               // 31..16
    const int b = G & 1, h = G >> 1;
    const size_t base = ((size_t)b * 2048) * 1024 + (size_t)h * 64;

    short8 qfA[2], qfB[2];
    {
        const size_t ra = base + (size_t)(qtA * 64 + wave * 16 + l16) * 1024;
        qfA[0] = *reinterpret_cast<const short8*>(Q + ra + quad * 8);
        qfA[1] = *reinterpret_cast<const short8*>(Q + ra + 32 + quad * 8);
        const size_t rb = base + (size_t)(qtB * 64 + wave * 16 + l16) * 1024;
        qfB[0] = *reinterpret_cast<const short8*>(Q + rb + quad * 8);
        qfB[1] = *reinterpret_cast<const short8*>(Q + rb + 32 + quad * 8);
    }

    float4v oA[4], oB[4];
#pragma unroll
    for (int i = 0; i < 4; i++) { oA[i] = (float4v){0.f,0.f,0.f,0.f}; oB[i] = (float4v){0.f,0.f,0.f,0.f}; }
    float sA = 0.f, sB = 0.f;               // row-sum partial for q = wave*16+l16

    const int srow = tid >> 2;             // 0..63 (coalesced: 4 lanes/row)
    const int cb   = (tid & 3) << 4;       // 0,16,32,48
    const int sxw  = srow ^ cb;            // swizzled s ((d>>4)<<4 == cb)

    const u16* Vp = V + base + (size_t)srow * 1024 + cb;
    const u16* kbase = K + base + (size_t)l16 * 1024 + quad * 8;
    int4 vr0 = *reinterpret_cast<const int4*>(Vp);          // tile 0
    int4 vr1 = *reinterpret_cast<const int4*>(Vp + 8);
    short8 kn[4][2], kc[4][2], vf[4][2];
#pragma unroll
    for (int nt = 0; nt < 4; nt++)                          // K tile 0
#pragma unroll
        for (int ks = 0; ks < 2; ks++)
            kn[nt][ks] = *reinterpret_cast<const short8*>(kbase + (size_t)(nt * 16) * 1024 + ks * 32);

    // prologue: stage tile 0 -> Vt[0]; then vr <- tile 1 (qtB >= 16 always)
    {
        const u16* a = reinterpret_cast<const u16*>(&vr0);
        const u16* c = reinterpret_cast<const u16*>(&vr1);
#pragma unroll
        for (int e = 0; e < 8; e++) Vt[0][(cb + e) * VSTR + sxw] = a[e];
#pragma unroll
        for (int e = 0; e < 8; e++) Vt[0][(cb + 8 + e) * VSTR + sxw] = c[e];
    }
    vr0 = *reinterpret_cast<const int4*>(Vp + 65536);
    vr1 = *reinterpret_cast<const int4*>(Vp + 65536 + 8);

    const int qloc = wave * 16 + l16;      // this lane's q within the 64-tile

    // SWAPPED QK: sacc[nt][r] = S[q=qloc][k = nt*16 + quad*4 + r]
    auto qk = [&](const short8 (&qf)[2], float4v (&sacc)[4]) {
#pragma unroll
        for (int nt = 0; nt < 4; nt++) {
            sacc[nt] = (float4v){0.f, 0.f, 0.f, 0.f};
#pragma unroll
            for (int ks = 0; ks < 2; ks++)
                sacc[nt] = __builtin_amdgcn_mfma_f32_16x16x32_bf16(kc[nt][ks], qf[ks], sacc[nt], 0, 0, 0);
        }
    };
    // softmax + pack; sigma-PV: pa[ks] = (w[2ks][0], w[2ks][1], w[2ks+1][0],
    // w[2ks+1][1]) -- lane-local, zero cross-lane ops.
    auto smx = [&](const float4v (&sacc)[4], float &sr, short8 (&pa)[2], bool diag) {
        unsigned int w[4][2];
#pragma unroll
        for (int nt = 0; nt < 4; nt++) {
            float p[4];
#pragma unroll
            for (int r = 0; r < 4; r++) {
                float sv = sacc[nt][r];                      // log2-domain
                if (diag && (nt * 16 + quad * 4 + r > qloc)) sv = -1e30f;
                p[r] = exp2f(sv);                            // masked -> 0
                sr += p[r];
            }
            asm("v_cvt_pk_bf16_f32 %0, %1, %2" : "=v"(w[nt][0]) : "v"(p[0]), "v"(p[1]));
            asm("v_cvt_pk_bf16_f32 %0, %1, %2" : "=v"(w[nt][1]) : "v"(p[2]), "v"(p[3]));
        }
        union { unsigned int u[4]; short8 s8; } t;
        t.u[0] = w[0][0]; t.u[1] = w[0][1]; t.u[2] = w[1][0]; t.u[3] = w[1][1];
        pa[0] = t.s8;
        t.u[0] = w[2][0]; t.u[1] = w[2][1]; t.u[2] = w[3][0]; t.u[3] = w[3][1];
        pa[1] = t.s8;
    };
    auto pv = [&](const short8 (&pa)[2], float4v (&oc)[4]) {
#pragma unroll
        for (int ks = 0; ks < 2; ks++)
#pragma unroll
            for (int dt = 0; dt < 4; dt++)
                oc[dt] = __builtin_amdgcn_mfma_f32_16x16x32_bf16(pa[ks], vf[dt][ks], oc[dt], 0, 0, 0);
    };

    for (int j = 0; j <= qtB; j++) {
        __syncthreads();   // protects Vt[(j+1)&1]: its iter-(j-1) readers done
        if (j < qtB) {     // stage tile j+1 (in vr) -> Vt[(j+1)&1]
            u16* D = Vt[(j + 1) & 1];
            const u16* a = reinterpret_cast<const u16*>(&vr0);
            const u16* c = reinterpret_cast<const u16*>(&vr1);
#pragma unroll
            for (int e = 0; e < 8; e++) D[(cb + e) * VSTR + sxw] = a[e];
#pragma unroll
            for (int e = 0; e < 8; e++) D[(cb + 8 + e) * VSTR + sxw] = c[e];
        }
#pragma unroll
        for (int nt = 0; nt < 4; nt++)
#pragma unroll
            for (int ks = 0; ks < 2; ks++) kc[nt][ks] = kn[nt][ks];
        if (j < qtB) {     // prefetch: V tile j+2, K tile j+1
            if (j + 2 <= qtB) {
                vr0 = *reinterpret_cast<const int4*>(Vp + (size_t)(j + 2) * 65536);
                vr1 = *reinterpret_cast<const int4*>(Vp + (size_t)(j + 2) * 65536 + 8);
            }
            const u16* kb2 = kbase + (size_t)(j + 1) * 65536;
#pragma unroll
            for (int nt = 0; nt < 4; nt++)
#pragma unroll
                for (int ks = 0; ks < 2; ks++)
                    kn[nt][ks] = *reinterpret_cast<const short8*>(kb2 + (size_t)(nt * 16) * 1024 + ks * 32);
        }
        // vf from Vt[j&1], sigma'd k-order: elem e reads V[k(e)][d],
        // k(e) = ks*32 + (e>>2)*16 + quad*4 + (e&3); phys k ^= (d>>4)<<4.
        {
            const u16* B = Vt[j & 1];
#pragma unroll
            for (int dt = 0; dt < 4; dt++) {
                const int rb = (dt * 16 + l16) * VSTR;
#pragma unroll
                for (int ks = 0; ks < 2; ks++) {
                    const int k1 = (ks * 32 + quad * 4) ^ (dt << 4);
                    const int k2 = (ks * 32 + 16 + quad * 4) ^ (dt << 4);
                    union { struct { uint2 lo, hi; } p; short8 s8; } u;
                    u.p.lo = *reinterpret_cast<const uint2*>(&B[rb + k1]);
                    u.p.hi = *reinterpret_cast<const uint2*>(&B[rb + k2]);
                    vf[dt][ks] = u.s8;
                }
            }
        }

        if (j <= qtA) {    // dual proc
            float4v xA[4], xB[4];
            qk(qfA, xA);
            qk(qfB, xB);
            short8 paA[2], paB[2];
            smx(xA, sA, paA, j == qtA);
            smx(xB, sB, paB, false);     // qtB >= 16 > qtA >= j: never diag
            pv(paA, oA);
            pv(paB, oB);
        } else {           // tail: only B remains
            float4v xB[4];
            qk(qfB, xB);
            short8 paB[2];
            smx(xB, sB, paB, j == qtB);
            pv(paB, oB);
        }
    }

    // epilogue: quad-reduce row sums, redistribute via shfl, normalize, write
    float tA = sA, tB = sB;
    tA += __shfl_xor(tA, 16); tA += __shfl_xor(tA, 32);
    tB += __shfl_xor(tB, 16); tB += __shfl_xor(tB, 32);
#pragma unroll
    for (int r = 0; r < 4; r++) {
        const int rl = quad * 4 + r;                 // q-local of o[.][r]
        const float invA = 1.0f / __shfl(tA, rl);    // lane rl holds q=wave*16+rl
        const float invB = 1.0f / __shfl(tB, rl);
        const size_t rowA = base + (size_t)(qtA * 64 + wave * 16 + rl) * 1024;
        const size_t rowB = base + (size_t)(qtB * 64 + wave * 16 + rl) * 1024;
#pragma unroll
        for (int dt = 0; dt < 4; dt++) {
            O[rowA + dt * 16 + l16] = f2b(oA[dt][r] * invA);
            O[rowB + dt * 16 + l16] = f2b(oB[dt][r] * invB);
        }
    }
}

// ---------------------------------------------------------------------------
extern "C" void kernel_launch(void* const* d_in, const int* in_sizes, int n_in,
                              void* d_out, int out_size, void* d_ws, size_t ws_size,
                              hipStream_t stream) {
    (void)in_sizes; (void)n_in; (void)out_size; (void)ws_size;
    const float* x  = (const float*)d_in[0];
    const float* wq = (const float*)d_in[1];
    const float* wk = (const float*)d_in[2];
    const float* wv = (const float*)d_in[3];
    const float* wo = (const float*)d_in[4];

    const size_t MN = (size_t)4096 * 1024;

    // d_out (16MB): xb (8MB) + wcat (6MB) + rope table (512KB in free tail);
    // all consumed before the final fp32 GEMM overwrites d_out.
    u16* xb   = (u16*)d_out;
    u16* wcat = xb + MN;                    // [3072][1024] = wq|wk|wv rows
    float2* tab = (float2*)(wcat + (size_t)3072 * 1024);
    u16* qbuf = (u16*)d_ws;                 // also attention output
    u16* kbuf = qbuf + MN;
    u16* vbuf = kbuf + MN;
    u16* wob  = vbuf + MN;                  // ws total: 26MB

    cvt_all<<<4352, 256, 0, stream>>>((const float4*)x, (const float4*)wq,
                                      (const float4*)wk, (const float4*)wv,
                                      (const float4*)wo, xb, wcat, wob, tab);
    gemm_qkv<<<256, 512, 0, stream>>>(xb, wcat, qbuf, kbuf, vbuf, tab);
    attn_kernel<<<512, 256, 0, stream>>>(qbuf, kbuf, vbuf, qbuf);
    gemm_proj<<<256, 512, 0, stream>>>(qbuf, wob, (float*)d_out);
}

// Round 12
// 213.841 us; speedup vs baseline: 1.1095x; 1.0203x over previous
//
#include <hip/hip_runtime.h>

// MHA forward, B=2, S=2048, D=1024, H=16, Dk=64, causal, RoPE. fp32 I/O.
// Internal bf16 MFMA 16x16x32, fp32 accum.
// History: attn FROZEN at R19 form (72us): R12/13/17/18/21 restructures
// FALSIFIED, R14/15/19 rewrites NEUTRAL -- 2-waves/SIMD latency floor.
// R20 WIN: QKV -> 256x192 dbuf 2-phase 1-blk/CU (228->217us). R22 proj
// port + rope-fusion NEUTRAL (218us); by subtraction qkv+proj ~ 125us.
// R23: T4 counted-vmcnt in BOTH GEMMs. The per-K-step __syncthreads
// forced vmcnt(0) -- draining the just-issued next-buffer loads (the m97
// ~20% structural stall). Now: raw s_barrier pair + s_waitcnt vmcnt(L)
// (L=7 qkv, 5 proj; oldest-first semantics) -- loads stay in flight ~2
// compute phases, never drained in the main loop. setprio(1) around MFMA
// cluster. sched_barrier(0) pins compiler motion (rule #18).

typedef unsigned short u16;
typedef __attribute__((ext_vector_type(8))) short short8;   // 8 bf16 = 4 VGPRs
typedef __attribute__((ext_vector_type(4))) float float4v;  // MFMA C/D

typedef const __attribute__((address_space(1))) void GV;    // global
typedef __attribute__((address_space(3))) void LV;          // LDS

#define VSTR 72   // attn Vt row stride (u16): 144B rows, 2-way read banks
#define QSCL 0.18033688011112042f   // 0.125 * log2(e)

__device__ __forceinline__ u16 f2b(float f) {
    union { float f; unsigned int i; } t; t.f = f;
    unsigned int r = t.i + 0x7fffu + ((t.i >> 16) & 1u);   // RNE
    return (u16)(r >> 16);
}

// ---------------- fused fp32 -> bf16 converter + RoPE table -----------------
// blocks 0..4095: cvt x/wq/wk/wv/wo. blocks 4096..4351: tab[pos*32+fi].
__global__ __launch_bounds__(256) void cvt_all(
    const float4* __restrict__ x,  const float4* __restrict__ wq,
    const float4* __restrict__ wk, const float4* __restrict__ wv,
    const float4* __restrict__ wo,
    u16* __restrict__ xb, u16* __restrict__ wcat, u16* __restrict__ wob,
    float2* __restrict__ tab)
{
    const int blk = blockIdx.x;
    if (blk >= 4096) {                 // RoPE cos/sin table
        const int i = (blk - 4096) * 256 + threadIdx.x;   // 0..65535
        const int pos = i >> 5, fi = i & 31;
        const float freq = exp2f((float)fi * -0.4152410118609203f);  // -log2(1e4)/32
        float sn, cs; sincosf((float)pos * freq, &sn, &cs);
        tab[i] = make_float2(cs, sn);
        return;
    }
    const int i = blk * 256 + threadIdx.x;
    const float4* s; u16* d; int off;
    if (i < 524288) { s = x; d = xb; off = i; }
    else {
        const int widx = i - 524288;
        const int w = widx >> 17, o = widx & 131071;
        switch (w) {
            case 0:  s = wq; d = wcat;              break;
            case 1:  s = wk; d = wcat + (1 << 20);  break;
            case 2:  s = wv; d = wcat + (2 << 20);  break;
            default: s = wo; d = wob;               break;
        }
        off = o;
    }
    float4 a = s[2 * off], b = s[2 * off + 1];
    u16 t[8] = {f2b(a.x), f2b(a.y), f2b(a.z), f2b(a.w),
                f2b(b.x), f2b(b.y), f2b(b.z), f2b(b.w)};
    reinterpret_cast<int4*>(d)[off] = *reinterpret_cast<int4*>(t);
}

// ---------------------------------------------------------------------------
// QKV GEMM: 256(m) x 192(n) x 64(k) steps, 512 threads, 8 waves (2m x 4n),
// double-buffered LDS (112KB). R23: counted-vmcnt schedule -- per K-step:
// vmcnt(7) [oldest 7 = buf cur landed] -> barrier -> MFMA (setprio 1) ->
// barrier -> refill buf cur with K-step kbi+2. No vmcnt(0) drain in loop.
// Grid 256 = 1 block/CU. RoPE epilogue.
// ---------------------------------------------------------------------------
__global__ __launch_bounds__(512) void gemm_qkv(
    const u16* __restrict__ X, const u16* __restrict__ Wb,
    u16* __restrict__ Yq, u16* __restrict__ Yk, u16* __restrict__ Yv,
    const float2* __restrict__ tab)
{
    __shared__ u16 As[2][256 * 64];   // 2 x 32KB
    __shared__ u16 Bs[2][192 * 64];   // 2 x 24KB

    const int tid  = threadIdx.x;
    const int wave = tid >> 6;                          // 0..7
    const int lane = tid & 63;
    const int quad = lane >> 4;
    const int l16  = lane & 15;
    const int wm = (wave >> 2) * 128;                   // 0,128
    const int wn = (wave & 3) * 48;                     // 0,48,96,144
    const int g = blockIdx.x;
    const int rr = g >> 3;                              // 0..31
    const int m0 = ((g & 7) * 2 + (rr >> 4)) * 256;     // 16 m-tiles
    const int n0 = (rr & 15) * 192;                     // 16 n-tiles
    const int lrow = lane >> 3;                         // 0..7 within 8-row slab
    const int cg8  = (lane & 7) ^ lrow;                 // swizzled global unit

    float4v acc[8][3];
#pragma unroll
    for (int mt = 0; mt < 8; mt++)
#pragma unroll
        for (int nt = 0; nt < 3; nt++) acc[mt][nt] = (float4v){0.f, 0.f, 0.f, 0.f};

    auto stage = [&](int bsel, int kb) {                // 7 loads/thread
#pragma unroll
        for (int t = 0; t < 4; t++) {                   // A: 32 slabs of 8 rows
            const int I = wave * 4 + t;
            const u16* gp = X + (size_t)(m0 + I * 8 + lrow) * 1024 + kb + cg8 * 8;
            __builtin_amdgcn_global_load_lds((GV*)gp, (LV*)&As[bsel][I * 512], 16, 0, 0);
        }
#pragma unroll
        for (int t = 0; t < 3; t++) {                   // B: 24 slabs of 8 rows
            const int I = wave * 3 + t;
            const u16* gp = Wb + (size_t)(n0 + I * 8 + lrow) * 1024 + kb + cg8 * 8;
            __builtin_amdgcn_global_load_lds((GV*)gp, (LV*)&Bs[bsel][I * 512], 16, 0, 0);
        }
    };

    stage(0, 0);
    stage(1, 64);                                       // 14 loads in flight

    for (int kbi = 0; kbi < 16; kbi++) {
        const int cur = kbi & 1;
        if (kbi < 15) { asm volatile("s_waitcnt vmcnt(7)" ::: "memory"); }
        else          { asm volatile("s_waitcnt vmcnt(0)" ::: "memory"); }
        __builtin_amdgcn_sched_barrier(0);
        __builtin_amdgcn_s_barrier();                   // all waves: buf[cur] ready
        __builtin_amdgcn_sched_barrier(0);
        __builtin_amdgcn_s_setprio(1);
#pragma unroll
        for (int ks = 0; ks < 2; ks++) {
            const int su = ((ks * 4 + quad) ^ (l16 & 7)) * 8;   // swizzled unit
            short8 af[8], bf[3];
#pragma unroll
            for (int t = 0; t < 8; t++)
                af[t] = *reinterpret_cast<const short8*>(&As[cur][(wm + t * 16 + l16) * 64 + su]);
#pragma unroll
            for (int t = 0; t < 3; t++)
                bf[t] = *reinterpret_cast<const short8*>(&Bs[cur][(wn + t * 16 + l16) * 64 + su]);
#pragma unroll
            for (int mt = 0; mt < 8; mt++)
#pragma unroll
                for (int nt = 0; nt < 3; nt++)
                    acc[mt][nt] = __builtin_amdgcn_mfma_f32_16x16x32_bf16(af[mt], bf[nt], acc[mt][nt], 0, 0, 0);
        }
        __builtin_amdgcn_s_setprio(0);
        __builtin_amdgcn_sched_barrier(0);
        __builtin_amdgcn_s_barrier();                   // all readers done
        __builtin_amdgcn_sched_barrier(0);
        if (kbi < 14) stage(cur, (kbi + 2) * 64);       // refill (overwrite safe)
    }

    // RoPE epilogue
#pragma unroll
    for (int nt = 0; nt < 3; nt++) {
        const int cg = n0 + wn + nt * 16 + l16;      // global col 0..3071
        const int buf = cg >> 10;                    // 0=q 1=k 2=v
        const int c = cg & 1023;
        u16* dst = (buf == 0) ? Yq : ((buf == 1) ? Yk : Yv);
        const bool rp = (buf < 2);
        const float scl = (buf == 0) ? QSCL : 1.0f;
        const int fi = (cg & 63) >> 1;               // pair index in head
#pragma unroll
        for (int mt = 0; mt < 8; mt++)
#pragma unroll
            for (int r = 0; r < 4; r++) {
                const int row = m0 + wm + mt * 16 + quad * 4 + r;
                float v = acc[mt][nt][r];
                if (rp) {
                    const float2 t = tab[((row & 2047) << 5) + fi];
                    const float partner = __shfl_xor(v, 1);
                    v = (l16 & 1) ? fmaf(v, t.x,  partner * t.y)
                                  : fmaf(v, t.x, -partner * t.y);
                }
                dst[(size_t)row * 1024 + c] = f2b(v * scl);
            }
    }
}

// ---------------------------------------------------------------------------
// Out-proj GEMM: 256(m) x 64(n) x 64(k) steps, 512 threads, 8 waves
// (4m x 2n), acc[4][2], dbuf LDS (80KB). R23: counted-vmcnt (L=5).
// Grid 256 = 1 block/CU. f32 output.
// ---------------------------------------------------------------------------
__global__ __launch_bounds__(512) void gemm_proj(
    const u16* __restrict__ X, const u16* __restrict__ Wb,
    float* __restrict__ Yf)
{
    __shared__ u16 As[2][256 * 64];   // 2 x 32KB
    __shared__ u16 Bs[2][64 * 64];    // 2 x 8KB

    const int tid  = threadIdx.x;
    const int wave = tid >> 6;                          // 0..7
    const int lane = tid & 63;
    const int quad = lane >> 4;
    const int l16  = lane & 15;
    const int wm = (wave >> 1) * 64;                    // 0,64,128,192
    const int wn = (wave & 1) * 32;                     // 0,32
    const int g = blockIdx.x;
    const int rr = g >> 3;                              // 0..31
    const int m0 = ((g & 7) * 2 + (rr >> 4)) * 256;     // 16 m-tiles
    const int n0 = (rr & 15) * 64;                      // 16 n-tiles
    const int lrow = lane >> 3;                         // 0..7 within 8-row slab
    const int cg8  = (lane & 7) ^ lrow;                 // swizzled global unit

    float4v acc[4][2];
#pragma unroll
    for (int mt = 0; mt < 4; mt++)
#pragma unroll
        for (int nt = 0; nt < 2; nt++) acc[mt][nt] = (float4v){0.f, 0.f, 0.f, 0.f};

    auto stage = [&](int bsel, int kb) {                // 5 loads/thread
#pragma unroll
        for (int t = 0; t < 4; t++) {                   // A: 32 slabs of 8 rows
            const int I = wave * 4 + t;
            const u16* gp = X + (size_t)(m0 + I * 8 + lrow) * 1024 + kb + cg8 * 8;
            __builtin_amdgcn_global_load_lds((GV*)gp, (LV*)&As[bsel][I * 512], 16, 0, 0);
        }
        {                                               // B: 8 slabs, 1/wave
            const u16* gp = Wb + (size_t)(n0 + wave * 8 + lrow) * 1024 + kb + cg8 * 8;
            __builtin_amdgcn_global_load_lds((GV*)gp, (LV*)&Bs[bsel][wave * 512], 16, 0, 0);
        }
    };

    stage(0, 0);
    stage(1, 64);                                       // 10 loads in flight

    for (int kbi = 0; kbi < 16; kbi++) {
        const int cur = kbi & 1;
        if (kbi < 15) { asm volatile("s_waitcnt vmcnt(5)" ::: "memory"); }
        else          { asm volatile("s_waitcnt vmcnt(0)" ::: "memory"); }
        __builtin_amdgcn_sched_barrier(0);
        __builtin_amdgcn_s_barrier();                   // all waves: buf[cur] ready
        __builtin_amdgcn_sched_barrier(0);
        __builtin_amdgcn_s_setprio(1);
#pragma unroll
        for (int ks = 0; ks < 2; ks++) {
            const int su = ((ks * 4 + quad) ^ (l16 & 7)) * 8;   // swizzled unit
            short8 af[4], bf[2];
#pragma unroll
            for (int t = 0; t < 4; t++)
                af[t] = *reinterpret_cast<const short8*>(&As[cur][(wm + t * 16 + l16) * 64 + su]);
#pragma unroll
            for (int t = 0; t < 2; t++)
                bf[t] = *reinterpret_cast<const short8*>(&Bs[cur][(wn + t * 16 + l16) * 64 + su]);
#pragma unroll
            for (int mt = 0; mt < 4; mt++)
#pragma unroll
                for (int nt = 0; nt < 2; nt++)
                    acc[mt][nt] = __builtin_amdgcn_mfma_f32_16x16x32_bf16(af[mt], bf[nt], acc[mt][nt], 0, 0, 0);
        }
        __builtin_amdgcn_s_setprio(0);
        __builtin_amdgcn_sched_barrier(0);
        __builtin_amdgcn_s_barrier();                   // all readers done
        __builtin_amdgcn_sched_barrier(0);
        if (kbi < 14) stage(cur, (kbi + 2) * 64);       // refill (overwrite safe)
    }

#pragma unroll
    for (int nt = 0; nt < 2; nt++) {
        const int col = n0 + wn + nt * 16 + l16;
#pragma unroll
        for (int mt = 0; mt < 4; mt++)
#pragma unroll
            for (int r = 0; r < 4; r++) {
                const int row = m0 + wm + mt * 16 + quad * 4 + r;
                Yf[(size_t)row * 1024 + col] = acc[mt][nt][r];
            }
    }
}

// ---------------------------------------------------------------------------
// Flash causal attention (FROZEN, R19/R20 form): paired q-tiles (qtA,
// 31-qtA) -> 512 equal-work blocks, 256 threads. Unnormalized softmax
// (q pre-scaled 0.125*log2e, p = exp2f(s)). Swapped QK^T: lane holds
// S[q=wave*16+l16][k=nt*16+quad*4+r]. sigma-PV: pa[ks] = packed own words
// (no cross-lane); vf = 2 x b64 at sigma'd k-offsets. Double-buffered Vt,
// ONE barrier/iter. K frags direct from global, prefetched. XCD grouping:
// 16 blocks of one (b,h) per XCD L2. O aliases Q.
// ---------------------------------------------------------------------------
__global__ __launch_bounds__(256, 2) void attn_kernel(
    const u16* Q, const u16* __restrict__ K,
    const u16* __restrict__ V, u16* O)
{
    __shared__ __align__(16) u16 Vt[2][64 * VSTR];   // Vt[b][d][s^((d>>4)<<4)]

    const int tid  = threadIdx.x;
    const int wave = tid >> 6;
    const int lane = tid & 63;
    const int quad = lane >> 4;
    const int l16  = lane & 15;
    const int g = blockIdx.x;
    const int xcd = g & 7, slot = g >> 3;
    const int G = (slot >> 4) * 8 + xcd;    // 0..31 = (b,h) group
    const int qtA = slot & 15;              // 0..15
    const int qtB = 31 - qtA;               // 31..16
    const int b = G & 1, h = G >> 1;
    const size_t base = ((size_t)b * 2048) * 1024 + (size_t)h * 64;

    short8 qfA[2], qfB[2];
    {
        const size_t ra = base + (size_t)(qtA * 64 + wave * 16 + l16) * 1024;
        qfA[0] = *reinterpret_cast<const short8*>(Q + ra + quad * 8);
        qfA[1] = *reinterpret_cast<const short8*>(Q + ra + 32 + quad * 8);
        const size_t rb = base + (size_t)(qtB * 64 + wave * 16 + l16) * 1024;
        qfB[0] = *reinterpret_cast<const short8*>(Q + rb + quad * 8);
        qfB[1] = *reinterpret_cast<const short8*>(Q + rb + 32 + quad * 8);
    }

    float4v oA[4], oB[4];
#pragma unroll
    for (int i = 0; i < 4; i++) { oA[i] = (float4v){0.f,0.f,0.f,0.f}; oB[i] = (float4v){0.f,0.f,0.f,0.f}; }
    float sA = 0.f, sB = 0.f;               // row-sum partial for q = wave*16+l16

    const int srow = tid >> 2;             // 0..63 (coalesced: 4 lanes/row)
    const int cb   = (tid & 3) << 4;       // 0,16,32,48
    const int sxw  = srow ^ cb;            // swizzled s ((d>>4)<<4 == cb)

    const u16* Vp = V + base + (size_t)srow * 1024 + cb;
    const u16* kbase = K + base + (size_t)l16 * 1024 + quad * 8;
    int4 vr0 = *reinterpret_cast<const int4*>(Vp);          // tile 0
    int4 vr1 = *reinterpret_cast<const int4*>(Vp + 8);
    short8 kn[4][2], kc[4][2], vf[4][2];
#pragma unroll
    for (int nt = 0; nt < 4; nt++)                          // K tile 0
#pragma unroll
        for (int ks = 0; ks < 2; ks++)
            kn[nt][ks] = *reinterpret_cast<const short8*>(kbase + (size_t)(nt * 16) * 1024 + ks * 32);

    // prologue: stage tile 0 -> Vt[0]; then vr <- tile 1 (qtB >= 16 always)
    {
        const u16* a = reinterpret_cast<const u16*>(&vr0);
        const u16* c = reinterpret_cast<const u16*>(&vr1);
#pragma unroll
        for (int e = 0; e < 8; e++) Vt[0][(cb + e) * VSTR + sxw] = a[e];
#pragma unroll
        for (int e = 0; e < 8; e++) Vt[0][(cb + 8 + e) * VSTR + sxw] = c[e];
    }
    vr0 = *reinterpret_cast<const int4*>(Vp + 65536);
    vr1 = *reinterpret_cast<const int4*>(Vp + 65536 + 8);

    const int qloc = wave * 16 + l16;      // this lane's q within the 64-tile

    // SWAPPED QK: sacc[nt][r] = S[q=qloc][k = nt*16 + quad*4 + r]
    auto qk = [&](const short8 (&qf)[2], float4v (&sacc)[4]) {
#pragma unroll
        for (int nt = 0; nt < 4; nt++) {
            sacc[nt] = (float4v){0.f, 0.f, 0.f, 0.f};
#pragma unroll
            for (int ks = 0; ks < 2; ks++)
                sacc[nt] = __builtin_amdgcn_mfma_f32_16x16x32_bf16(kc[nt][ks], qf[ks], sacc[nt], 0, 0, 0);
        }
    };
    // softmax + pack; sigma-PV: pa[ks] = (w[2ks][0], w[2ks][1], w[2ks+1][0],
    // w[2ks+1][1]) -- lane-local, zero cross-lane ops.
    auto smx = [&](const float4v (&sacc)[4], float &sr, short8 (&pa)[2], bool diag) {
        unsigned int w[4][2];
#pragma unroll
        for (int nt = 0; nt < 4; nt++) {
            float p[4];
#pragma unroll
            for (int r = 0; r < 4; r++) {
                float sv = sacc[nt][r];                      // log2-domain
                if (diag && (nt * 16 + quad * 4 + r > qloc)) sv = -1e30f;
                p[r] = exp2f(sv);                            // masked -> 0
                sr += p[r];
            }
            asm("v_cvt_pk_bf16_f32 %0, %1, %2" : "=v"(w[nt][0]) : "v"(p[0]), "v"(p[1]));
            asm("v_cvt_pk_bf16_f32 %0, %1, %2" : "=v"(w[nt][1]) : "v"(p[2]), "v"(p[3]));
        }
        union { unsigned int u[4]; short8 s8; } t;
        t.u[0] = w[0][0]; t.u[1] = w[0][1]; t.u[2] = w[1][0]; t.u[3] = w[1][1];
        pa[0] = t.s8;
        t.u[0] = w[2][0]; t.u[1] = w[2][1]; t.u[2] = w[3][0]; t.u[3] = w[3][1];
        pa[1] = t.s8;
    };
    auto pv = [&](const short8 (&pa)[2], float4v (&oc)[4]) {
#pragma unroll
        for (int ks = 0; ks < 2; ks++)
#pragma unroll
            for (int dt = 0; dt < 4; dt++)
                oc[dt] = __builtin_amdgcn_mfma_f32_16x16x32_bf16(pa[ks], vf[dt][ks], oc[dt], 0, 0, 0);
    };

    for (int j = 0; j <= qtB; j++) {
        __syncthreads();   // protects Vt[(j+1)&1]: its iter-(j-1) readers done
        if (j < qtB) {     // stage tile j+1 (in vr) -> Vt[(j+1)&1]
            u16* D = Vt[(j + 1) & 1];
            const u16* a = reinterpret_cast<const u16*>(&vr0);
            const u16* c = reinterpret_cast<const u16*>(&vr1);
#pragma unroll
            for (int e = 0; e < 8; e++) D[(cb + e) * VSTR + sxw] = a[e];
#pragma unroll
            for (int e = 0; e < 8; e++) D[(cb + 8 + e) * VSTR + sxw] = c[e];
        }
#pragma unroll
        for (int nt = 0; nt < 4; nt++)
#pragma unroll
            for (int ks = 0; ks < 2; ks++) kc[nt][ks] = kn[nt][ks];
        if (j < qtB) {     // prefetch: V tile j+2, K tile j+1
            if (j + 2 <= qtB) {
                vr0 = *reinterpret_cast<const int4*>(Vp + (size_t)(j + 2) * 65536);
                vr1 = *reinterpret_cast<const int4*>(Vp + (size_t)(j + 2) * 65536 + 8);
            }
            const u16* kb2 = kbase + (size_t)(j + 1) * 65536;
#pragma unroll
            for (int nt = 0; nt < 4; nt++)
#pragma unroll
                for (int ks = 0; ks < 2; ks++)
                    kn[nt][ks] = *reinterpret_cast<const short8*>(kb2 + (size_t)(nt * 16) * 1024 + ks * 32);
        }
        // vf from Vt[j&1], sigma'd k-order: elem e reads V[k(e)][d],
        // k(e) = ks*32 + (e>>2)*16 + quad*4 + (e&3); phys k ^= (d>>4)<<4.
        {
            const u16* B = Vt[j & 1];
#pragma unroll
            for (int dt = 0; dt < 4; dt++) {
                const int rb = (dt * 16 + l16) * VSTR;
#pragma unroll
                for (int ks = 0; ks < 2; ks++) {
                    const int k1 = (ks * 32 + quad * 4) ^ (dt << 4);
                    const int k2 = (ks * 32 + 16 + quad * 4) ^ (dt << 4);
                    union { struct { uint2 lo, hi; } p; short8 s8; } u;
                    u.p.lo = *reinterpret_cast<const uint2*>(&B[rb + k1]);
                    u.p.hi = *reinterpret_cast<const uint2*>(&B[rb + k2]);
                    vf[dt][ks] = u.s8;
                }
            }
        }

        if (j <= qtA) {    // dual proc
            float4v xA[4], xB[4];
            qk(qfA, xA);
            qk(qfB, xB);
            short8 paA[2], paB[2];
            smx(xA, sA, paA, j == qtA);
            smx(xB, sB, paB, false);     // qtB >= 16 > qtA >= j: never diag
            pv(paA, oA);
            pv(paB, oB);
        } else {           // tail: only B remains
            float4v xB[4];
            qk(qfB, xB);
            short8 paB[2];
            smx(xB, sB, paB, j == qtB);
            pv(paB, oB);
        }
    }

    // epilogue: quad-reduce row sums, redistribute via shfl, normalize, write
    float tA = sA, tB = sB;
    tA += __shfl_xor(tA, 16); tA += __shfl_xor(tA, 32);
    tB += __shfl_xor(tB, 16); tB += __shfl_xor(tB, 32);
#pragma unroll
    for (int r = 0; r < 4; r++) {
        const int rl = quad * 4 + r;                 // q-local of o[.][r]
        const float invA = 1.0f / __shfl(tA, rl);    // lane rl holds q=wave*16+rl
        const float invB = 1.0f / __shfl(tB, rl);
        const size_t rowA = base + (size_t)(qtA * 64 + wave * 16 + rl) * 1024;
        const size_t rowB = base + (size_t)(qtB * 64 + wave * 16 + rl) * 1024;
#pragma unroll
        for (int dt = 0; dt < 4; dt++) {
            O[rowA + dt * 16 + l16] = f2b(oA[dt][r] * invA);
            O[rowB + dt * 16 + l16] = f2b(oB[dt][r] * invB);
        }
    }
}

// ---------------------------------------------------------------------------
extern "C" void kernel_launch(void* const* d_in, const int* in_sizes, int n_in,
                              void* d_out, int out_size, void* d_ws, size_t ws_size,
                              hipStream_t stream) {
    (void)in_sizes; (void)n_in; (void)out_size; (void)ws_size;
    const float* x  = (const float*)d_in[0];
    const float* wq = (const float*)d_in[1];
    const float* wk = (const float*)d_in[2];
    const float* wv = (const float*)d_in[3];
    const float* wo = (const float*)d_in[4];

    const size_t MN = (size_t)4096 * 1024;

    // d_out (16MB): xb (8MB) + wcat (6MB) + rope table (512KB in free tail);
    // all consumed before the final fp32 GEMM overwrites d_out.
    u16* xb   = (u16*)d_out;
    u16* wcat = xb + MN;                    // [3072][1024] = wq|wk|wv rows
    float2* tab = (float2*)(wcat + (size_t)3072 * 1024);
    u16* qbuf = (u16*)d_ws;                 // also attention output
    u16* kbuf = qbuf + MN;
    u16* vbuf = kbuf + MN;
    u16* wob  = vbuf + MN;                  // ws total: 26MB

    cvt_all<<<4352, 256, 0, stream>>>((const float4*)x, (const float4*)wq,
                                      (const float4*)wk, (const float4*)wv,
                                      (const float4*)wo, xb, wcat, wob, tab);
    gemm_qkv<<<256, 512, 0, stream>>>(xb, wcat, qbuf, kbuf, vbuf, tab);
    attn_kernel<<<512, 256, 0, stream>>>(qbuf, kbuf, vbuf, qbuf);
    gemm_proj<<<256, 512, 0, stream>>>(qbuf, wob, (float*)d_out);
}